// Round 3
// baseline (91.891 us; speedup 1.0000x reference)
//
#include <hip/hip_runtime.h>

// PointsRenderer: B=4, N=100000, F=64, S=256, K=8, R=2/256
// out = (B, F+1, S, S) f32: channels 0..63 = composited features, 64 = depth.

#define BB 4
#define NN 100000
#define FF 64
#define SS 256
#define KK 8
#define BN (BB * NN)          // 400000
#define RR_INV 16384.0f       // 1 / (r*r),  r = 2*1.0/256

__global__ __launch_bounds__(256)
void points_render_kernel(const float* __restrict__ features, // [BN][FF]
                          const int*   __restrict__ idx,      // [B][S][S][K] int32
                          const float* __restrict__ zbuf,     // [B][S][S][K]
                          const float* __restrict__ dist,     // [B][S][S][K]
                          float* __restrict__ out)            // [B][FF+1][S][S]
{
    // Block covers 64 consecutive x-pixels of one row (b, y).
    __shared__ float  tile[64][FF + 1];   // [local x][channel], stride 65 -> 2-way (free)
    __shared__ float2 s_oc[64][KK];       // .x = contrib, .y = row byte-offset (bitcast)

    const int tid  = threadIdx.x;
    const int wave = tid >> 6;
    const int lane = tid & 63;

    const int blk = blockIdx.x;           // 4096 blocks
    const int xb  = blk & 3;
    const int y   = (blk >> 2) & (SS - 1);
    const int b   = blk >> 10;
    const int x0  = xb * 64;

    const long long pixbase = (((long long)b * SS + y) * SS + x0);

    // ---- Phase A: lane-parallel compositing weights (lane = pixel) ----
    if (tid < 64) {
        const long long p = pixbase + tid;
        const float4* d4 = (const float4*)(dist + p * KK);
        const float4* z4 = (const float4*)(zbuf + p * KK);
        const int4*   i4 = (const int4*)(idx  + p * KK);
        float4 da = d4[0], db = d4[1];
        float4 za = z4[0], zb = z4[1];
        int4   ia = i4[0], ib = i4[1];

        float dd[KK] = {da.x, da.y, da.z, da.w, db.x, db.y, db.z, db.w};
        float zz[KK] = {za.x, za.y, za.z, za.w, zb.x, zb.y, zb.z, zb.w};
        int   ii[KK] = {ia.x, ia.y, ia.z, ia.w, ib.x, ib.y, ib.z, ib.w};

        float trans = 1.0f, wsum = 0.0f, depth = 0.0f;
        #pragma unroll
        for (int k = 0; k < KK; ++k) {
            float a  = __expf(-fmaxf(dd[k] * RR_INV, 0.0f));
            float we = fminf(a, 0.99f);
            if (ii[k] < 0) we = 0.0f;                 // valid mask
            float2 oc;
            oc.x = we * trans;
            trans *= (1.0f - we);
            wsum  += we;
            depth += zz[k] * we;

            int si = ii[k];
            si = si < 0 ? 0 : (si > BN - 1 ? BN - 1 : si);  // safe_idx
            oc.y = __int_as_float(si << 8);                 // si * 256 bytes/row
            s_oc[tid][k] = oc;
        }
        tile[tid][FF] = depth / fmaxf(wsum, 1e-9f);
    }
    __syncthreads();

    // ---- Phase B: fat gathers. Wave w owns pixels [w*16, w*16+16). ----
    // Lane l: k-group sub = l>>4 (handles k = sub and k = sub+4),
    //         feature bytes fb = (l&15)*16 (one float4 of the row).
    // One dwordx4 instruction gathers 4 full 256B rows -> 1KB in flight each.
    const int sub = lane >> 4;
    const unsigned fb = (unsigned)((lane & 15) * 16);
    const char* fbase = (const char*)features;

    #pragma unroll 4
    for (int i = 0; i < 16; ++i) {
        const int xl = wave * 16 + i;
        const float2 e0 = s_oc[xl][sub];       // ds_read_b64, 4-addr broadcast
        const float2 e1 = s_oc[xl][sub + 4];
        const unsigned o0 = (unsigned)__float_as_int(e0.y) + fb;
        const unsigned o1 = (unsigned)__float_as_int(e1.y) + fb;
        const float4 g0 = *(const float4*)(fbase + o0);   // 1KB/instr gather
        const float4 g1 = *(const float4*)(fbase + o1);

        float4 acc;
        acc.x = g0.x * e0.x + g1.x * e1.x;
        acc.y = g0.y * e0.x + g1.y * e1.x;
        acc.z = g0.z * e0.x + g1.z * e1.x;
        acc.w = g0.w * e0.x + g1.w * e1.x;

        // butterfly over lane bits 4,5: sum the 4 k-groups per feature column
        acc.x += __shfl_xor(acc.x, 16);
        acc.y += __shfl_xor(acc.y, 16);
        acc.z += __shfl_xor(acc.z, 16);
        acc.w += __shfl_xor(acc.w, 16);
        acc.x += __shfl_xor(acc.x, 32);
        acc.y += __shfl_xor(acc.y, 32);
        acc.z += __shfl_xor(acc.z, 32);
        acc.w += __shfl_xor(acc.w, 32);

        if (sub == 0) {                       // lanes 0..15 own the final sums
            const int c = (lane & 15) * 4;    // scalar b32 writes: stride-65 stays
            tile[xl][c + 0] = acc.x;          // 16B-alignment-safe, 2-way banks
            tile[xl][c + 1] = acc.y;
            tile[xl][c + 2] = acc.z;
            tile[xl][c + 3] = acc.w;
        }
    }
    __syncthreads();

    // ---- Write 64 x 65 floats: contiguous 256B channel segments ----
    float* outb = out + (long long)b * (FF + 1) * SS * SS + (long long)y * SS + x0;
    for (int j = tid; j < 64 * (FF + 1); j += 256) {
        const int c  = j >> 6;
        const int xl = j & 63;
        outb[(long long)c * (SS * SS) + xl] = tile[xl][c];
    }
}

extern "C" void kernel_launch(void* const* d_in, const int* in_sizes, int n_in,
                              void* d_out, int out_size, void* d_ws, size_t ws_size,
                              hipStream_t stream) {
    const float* features = (const float*)d_in[0];
    const int*   idx      = (const int*)d_in[1];
    const float* zbuf     = (const float*)d_in[2];
    const float* dist     = (const float*)d_in[3];
    float* out = (float*)d_out;

    const int nblocks = (BB * SS * SS) / 64;   // 4096
    points_render_kernel<<<dim3(nblocks), dim3(256), 0, stream>>>(
        features, idx, zbuf, dist, out);
}